// Round 9
// baseline (1275.353 us; speedup 1.0000x reference)
//
#include <hip/hip_runtime.h>
#include <hip/hip_cooperative_groups.h>

namespace cg = cooperative_groups;

typedef float v2f __attribute__((ext_vector_type(2)));

#define NPTS    6144
#define RESCALE (1.0f / 1024.0f)  // per-iteration overflow guard (cancels at final normalize)

// ---------------- fused cooperative kernel geometry ----------------
// 1024 blocks x 256 thr = 4 blocks/CU, 16 waves/CU -- well inside the
// cooperative co-residency limit (R8 failed at the exact 2048 boundary).
#define IBLK   256
#define IPT    6                  // i's per thread -> 3 packed float2 chains
#define NCH    (IPT / 2)
#define ISPAN  (IBLK * IPT)       // 1536
#define NIBLK  (NPTS / ISPAN)     // 4
#define JPART  256
#define JLEN   (NPTS / JPART)     // 24
#define GRIDSZ (NIBLK * JPART)    // 1024
#define PPB    (NPTS / GRIDSZ)    // 6

template <bool ONES>
__device__ __forceinline__ void matvec_phase(
    const float4* __restrict__ rec, const float* __restrict__ z3a,
    const float* __restrict__ vsrc, float* __restrict__ vdst,
    float* __restrict__ vzero, int i0, int jp,
    const v2f* X2, const v2f* Y2, const v2f* X3, const v2f* Y3, const v2f* Z3)
{
  if (jp == 0) {                       // zero the dst-after-next buffer
#pragma unroll
    for (int u = 0; u < IPT; ++u) vzero[i0 + u * IBLK] = 0.0f;
  }
  v2f acc[NCH];
#pragma unroll
  for (int c = 0; c < NCH; ++c) acc[c] = (v2f){0.0f, 0.0f};

  const v2f kM100 = (v2f){-100.0f, -100.0f};
  const v2f k200  = (v2f){ 200.0f,  200.0f};
  const v2f kOne  = (v2f){   1.0f,    1.0f};
  const v2f kZero = (v2f){   0.0f,    0.0f};

  const int j0 = jp * JLEN;
#pragma unroll 4
  for (int jj = 0; jj < JLEN; ++jj) {
    const int j = j0 + jj;             // wave-uniform -> scalar/broadcast loads
    const float4 rj = rec[j];
    const float  zj = z3a[j];
    const float  vj = ONES ? 1.0f : vsrc[j];
#pragma unroll
    for (int c = 0; c < NCH; ++c) {
      v2f dx = X2[c] - rj.x, dy = Y2[c] - rj.y;
      v2f a  = __builtin_elementwise_fma(dy, dy, dx * dx);              // ||dp2||^2
      v2f ex = X3[c] - rj.z, ey = Y3[c] - rj.w, ez = Z3[c] - zj;
      v2f b  = __builtin_elementwise_fma(
                   ez, ez, __builtin_elementwise_fma(ey, ey, ex * ex)); // ||dp3||^2
      v2f ab = a * b;
      v2f s  = (v2f){__builtin_amdgcn_sqrtf(ab.x),
                     __builtin_amdgcn_sqrtf(ab.y)};                     // bare v_sqrt_f32
      // (d2-d3)^2 = a+b-2*sqrt(ab);  S = max(0, 1 - 100*(a+b) + 200*sqrt(ab))
      v2f w  = __builtin_elementwise_fma(a + b, kM100, kOne);
      w = __builtin_elementwise_fma(s, k200, w);
      w = __builtin_elementwise_max(w, kZero);
      acc[c] = __builtin_elementwise_fma(w, (v2f){vj, vj}, acc[c]);
    }
  }
#pragma unroll
  for (int c = 0; c < NCH; ++c) {
    atomicAdd(&vdst[i0 + (2 * c + 0) * IBLK], acc[c].x * RESCALE);
    atomicAdd(&vdst[i0 + (2 * c + 1) * IBLK], acc[c].y * RESCALE);
  }
}

// One persistent cooperative kernel: prep -> 10 power iterations -> finalize.
__global__ __launch_bounds__(IBLK, 4) void power_kernel(
    const float* __restrict__ p2, const float* __restrict__ p3,
    float4* __restrict__ rec, float* __restrict__ z3a,
    float* __restrict__ b0, float* __restrict__ b1, float* __restrict__ b2,
    float* __restrict__ out)
{
  cg::grid_group grid = cg::this_grid();
  const int tid = threadIdx.x;
  const int ib  = blockIdx.x % NIBLK;
  const int jp  = blockIdx.x / NIBLK;
  const int i0  = ib * ISPAN + tid;

  // ---- prep: pack f32 SoA; zero b1 (iter-0 dst). b0 stays poison (never read). ----
  if (tid < PPB) {
    int i = blockIdx.x * PPB + tid;
    float x2 = p2[2 * i], y2 = p2[2 * i + 1];
    float x3 = p3[3 * i], y3 = p3[3 * i + 1], z3 = p3[3 * i + 2];
    rec[i] = make_float4(x2, y2, x3, y3);
    z3a[i] = z3;
    b1[i]  = 0.0f;
  }
  grid.sync();

  // ---- i-side fragments: loaded ONCE, live in registers across all 10 iterations ----
  v2f X2[NCH], Y2[NCH], X3[NCH], Y3[NCH], Z3[NCH];
#pragma unroll
  for (int c = 0; c < NCH; ++c) {
    const int ia  = i0 + (2 * c + 0) * IBLK;
    const int ib2 = i0 + (2 * c + 1) * IBLK;
    float4 ra = rec[ia], rb = rec[ib2];
    X2[c] = (v2f){ra.x, rb.x};
    Y2[c] = (v2f){ra.y, rb.y};
    X3[c] = (v2f){ra.z, rb.z};
    Y3[c] = (v2f){ra.w, rb.w};
    Z3[c] = (v2f){z3a[ia], z3a[ib2]};
  }

  // ---- iter 0: v = ones (no vsrc read), dst=b1, zero=b2 ----
  matvec_phase<true>(rec, z3a, b0, b1, b2, i0, jp, X2, Y2, X3, Y3, Z3);

  // ---- iters 1..9: rotate (src,dst,zero); grid.sync separates iterations ----
  const float* vs = b1; float* vd = b2; float* vz = b0;
#pragma unroll 1
  for (int k = 1; k < 10; ++k) {
    grid.sync();
    matvec_phase<false>(rec, z3a, vs, vd, vz, i0, jp, X2, Y2, X3, Y3, Z3);
    float* t = (float*)vs; vs = vd; vd = vz; vz = t;
  }
  grid.sync();

  // ---- finalize: result in b1; jp==0 blocks normalize + store their i-slice ----
  if (jp == 0) {
    float ss = 0.0f;
    for (int k = tid; k < NPTS; k += IBLK) {
      float x = b1[k];
      ss = fmaf(x, x, ss);
    }
    for (int off = 32; off > 0; off >>= 1) ss += __shfl_down(ss, off, 64);
    __shared__ float wsum[4];
    if ((tid & 63) == 0) wsum[tid >> 6] = ss;
    __syncthreads();
    float inv = 1.0f / (sqrtf(wsum[0] + wsum[1] + wsum[2] + wsum[3]) + 1e-6f);
#pragma unroll
    for (int u = 0; u < IPT; ++u) {
      int i = i0 + u * IBLK;
      out[i] = b1[i] * inv;
    }
  }
}

// ---------------- fallback: proven R7 multi-launch path (199.6 us) ----------------
#define FB_IPT    4
#define FB_NCH    2
#define FB_IBLK   128
#define FB_ISPAN  (FB_IBLK * FB_IPT)   // 512
#define FB_NIBLK  (NPTS / FB_ISPAN)    // 12
#define FB_JPART  384
#define FB_JLEN   (NPTS / FB_JPART)    // 16

__global__ __launch_bounds__(FB_IBLK) void fb_prep_kernel(
    const float* __restrict__ p2, const float* __restrict__ p3,
    float4* __restrict__ rec, float* __restrict__ z3a,
    float* __restrict__ vA, float* __restrict__ vB) {
  int i = blockIdx.x * FB_IBLK + threadIdx.x;
  if (i >= NPTS) return;
  rec[i] = make_float4(p2[2 * i], p2[2 * i + 1], p3[3 * i], p3[3 * i + 1]);
  z3a[i] = p3[3 * i + 2];
  vA[i] = 1.0f;
  vB[i] = 0.0f;
}

__global__ __launch_bounds__(FB_IBLK) void fb_matvec_kernel(
    const float4* __restrict__ rec, const float* __restrict__ z3a,
    const float* __restrict__ vsrc, float* __restrict__ vdst,
    float* __restrict__ vzero) {
  const int ib = blockIdx.x % FB_NIBLK;
  const int jp = blockIdx.x / FB_NIBLK;
  const int i0 = ib * FB_ISPAN + threadIdx.x;

  const int j0 = jp * FB_JLEN;
  float4 RJ[FB_JLEN];
  float  ZJ[FB_JLEN], VJ[FB_JLEN];
#pragma unroll
  for (int jj = 0; jj < FB_JLEN; ++jj) {
    RJ[jj] = rec[j0 + jj]; ZJ[jj] = z3a[j0 + jj]; VJ[jj] = vsrc[j0 + jj];
  }

  v2f X2[FB_NCH], Y2[FB_NCH], X3[FB_NCH], Y3[FB_NCH], Z3[FB_NCH], acc[FB_NCH];
#pragma unroll
  for (int c = 0; c < FB_NCH; ++c) {
    const int ia  = i0 + (2 * c + 0) * FB_IBLK;
    const int ib2 = i0 + (2 * c + 1) * FB_IBLK;
    float4 ra = rec[ia], rb = rec[ib2];
    X2[c] = (v2f){ra.x, rb.x}; Y2[c] = (v2f){ra.y, rb.y};
    X3[c] = (v2f){ra.z, rb.z}; Y3[c] = (v2f){ra.w, rb.w};
    Z3[c] = (v2f){z3a[ia], z3a[ib2]};
    acc[c] = (v2f){0.0f, 0.0f};
    if (jp == 0) { vzero[ia] = 0.0f; vzero[ib2] = 0.0f; }
  }

  const v2f kM100 = (v2f){-100.0f, -100.0f};
  const v2f k200  = (v2f){ 200.0f,  200.0f};
  const v2f kOne  = (v2f){   1.0f,    1.0f};
  const v2f kZero = (v2f){   0.0f,    0.0f};

#pragma unroll
  for (int jj = 0; jj < FB_JLEN; ++jj) {
    const float4 rj = RJ[jj];
    const float  zj = ZJ[jj];
    const float  vj = VJ[jj];
#pragma unroll
    for (int c = 0; c < FB_NCH; ++c) {
      v2f dx = X2[c] - rj.x, dy = Y2[c] - rj.y;
      v2f a  = __builtin_elementwise_fma(dy, dy, dx * dx);
      v2f ex = X3[c] - rj.z, ey = Y3[c] - rj.w, ez = Z3[c] - zj;
      v2f b  = __builtin_elementwise_fma(
                   ez, ez, __builtin_elementwise_fma(ey, ey, ex * ex));
      v2f ab = a * b;
      v2f s  = (v2f){__builtin_amdgcn_sqrtf(ab.x), __builtin_amdgcn_sqrtf(ab.y)};
      v2f w  = __builtin_elementwise_fma(a + b, kM100, kOne);
      w = __builtin_elementwise_fma(s, k200, w);
      w = __builtin_elementwise_max(w, kZero);
      acc[c] = __builtin_elementwise_fma(w, (v2f){vj, vj}, acc[c]);
    }
  }
#pragma unroll
  for (int c = 0; c < FB_NCH; ++c) {
    atomicAdd(&vdst[i0 + (2 * c + 0) * FB_IBLK], acc[c].x * RESCALE);
    atomicAdd(&vdst[i0 + (2 * c + 1) * FB_IBLK], acc[c].y * RESCALE);
  }
}

__global__ __launch_bounds__(256) void fb_finalize_kernel(
    const float* __restrict__ v, float* __restrict__ out) {
  const int tid = threadIdx.x;
  float ss = 0.0f;
  for (int k = tid; k < NPTS; k += 256) { float x = v[k]; ss = fmaf(x, x, ss); }
  for (int off = 32; off > 0; off >>= 1) ss += __shfl_down(ss, off, 64);
  __shared__ float wsum[4];
  if ((tid & 63) == 0) wsum[tid >> 6] = ss;
  __syncthreads();
  float inv = 1.0f / (sqrtf(wsum[0] + wsum[1] + wsum[2] + wsum[3]) + 1e-6f);
  int i = blockIdx.x * 256 + tid;
  out[i] = v[i] * inv;
}

extern "C" void kernel_launch(void* const* d_in, const int* in_sizes, int n_in,
                              void* d_out, int out_size, void* d_ws, size_t ws_size,
                              hipStream_t stream) {
  const float* p2 = (const float*)d_in[0];   // 6144 x 2, float32
  const float* p3 = (const float*)d_in[1];   // 6144 x 3, float32
  float* out = (float*)d_out;                // 6144, float32

  float* w = (float*)d_ws;
  float4* rec = (float4*)w;                  // 6144 float4
  float*  z3a = w + 24576;                   // 6144
  float*  b0  = w + 32768;
  float*  b1  = w + 40960;
  float*  b2  = w + 49152;

  void* args[] = { (void*)&p2, (void*)&p3, (void*)&rec, (void*)&z3a,
                   (void*)&b0, (void*)&b1, (void*)&b2, (void*)&out };
  hipError_t err = hipLaunchCooperativeKernel((const void*)power_kernel,
                                              dim3(GRIDSZ), dim3(IBLK),
                                              args, 0, stream);
  if (err != hipSuccess) {
    // Deterministic fallback: proven multi-launch path (R7).
    (void)hipGetLastError();   // clear sticky error
    fb_prep_kernel<<<NPTS / FB_IBLK, FB_IBLK, 0, stream>>>(p2, p3, rec, z3a, b0, b1);
    float* buf[3] = { b0, b1, b2 };
    for (int k = 0; k < 10; ++k) {
      fb_matvec_kernel<<<FB_NIBLK * FB_JPART, FB_IBLK, 0, stream>>>(
          rec, z3a, buf[k % 3], buf[(k + 1) % 3], buf[(k + 2) % 3]);
    }
    fb_finalize_kernel<<<NPTS / 256, 256, 0, stream>>>(buf[1], out);
  }
}

// Round 10
// 255.001 us; speedup vs baseline: 5.0014x; 5.0014x over previous
//
#include <hip/hip_runtime.h>

#define NPTS   6144
#define IBLK   64                 // ONE wave per block: independent retire/refill, no convoy
#define IPT    8                  // 8 independent scalar FMA chains per thread
#define ISPAN  (IBLK * IPT)       // 512 i's per block
#define NIBLK  (NPTS / ISPAN)     // 12 i-blocks
#define JPART  256                // -> 3072 blocks = 3072 waves = 3 waves/SIMD resident
#define JLEN   (NPTS / JPART)     // 24 j's per partition
#define RESCALE (1.0f / 1024.0f)  // per-iteration overflow guard (cancels at final normalize)

// Pack f32 inputs into SoA for clean uniform loads; init v buffers.
__global__ __launch_bounds__(128) void prep_kernel(
    const float* __restrict__ p2, const float* __restrict__ p3,
    float4* __restrict__ rec, float* __restrict__ z3a,
    float* __restrict__ vA, float* __restrict__ vB) {
  int i = blockIdx.x * 128 + threadIdx.x;
  if (i >= NPTS) return;
  rec[i] = make_float4(p2[2 * i], p2[2 * i + 1], p3[3 * i], p3[3 * i + 1]);
  z3a[i] = p3[3 * i + 2];
  vA[i] = 1.0f;   // v0 = ones
  vB[i] = 0.0f;   // iter0 atomic target
}

// y[i] += (1/1024) * sum_j S(i,j) * v[j], j in this block's partition.
// Scalar math only (known-good lowering: v_sub/v_fma/v_max + bare v_sqrt).
// IPT=8 chains: issue distance 8x2cyc=16 >> 4-cyc FMA latency -> no dep stalls;
// j-side uniform loads amortized 8x. Also zeroes the dst-after-next buffer.
__global__ __launch_bounds__(IBLK) void matvec_kernel(
    const float4* __restrict__ rec, const float* __restrict__ z3a,
    const float* __restrict__ vsrc, float* __restrict__ vdst,
    float* __restrict__ vzero) {
  const int ib = blockIdx.x % NIBLK;
  const int jp = blockIdx.x / NIBLK;
  const int i0 = ib * ISPAN + threadIdx.x;

  float xi2[IPT], yi2[IPT], xi3[IPT], yi3[IPT], zi3[IPT], acc[IPT];
#pragma unroll
  for (int u = 0; u < IPT; ++u) {
    const int i = i0 + u * IBLK;
    float4 r = rec[i];
    xi2[u] = r.x; yi2[u] = r.y; xi3[u] = r.z; yi3[u] = r.w;
    zi3[u] = z3a[i];
    acc[u] = 0.0f;
    if (jp == 0) vzero[i] = 0.0f;   // prepare next-next iteration's dst
  }

  const int j0 = jp * JLEN;
#pragma unroll 4
  for (int jj = 0; jj < JLEN; ++jj) {
    const int j = j0 + jj;          // wave-uniform -> broadcast loads
    const float4 rj = rec[j];
    const float  zj = z3a[j];
    const float  vj = vsrc[j];
#pragma unroll
    for (int u = 0; u < IPT; ++u) {
      float dx = xi2[u] - rj.x, dy = yi2[u] - rj.y;
      float a  = fmaf(dy, dy, dx * dx);                     // ||dp2||^2
      float ex = xi3[u] - rj.z, ey = yi3[u] - rj.w, ez = zi3[u] - zj;
      float b  = fmaf(ez, ez, fmaf(ey, ey, ex * ex));       // ||dp3||^2
      float s  = __builtin_amdgcn_sqrtf(a * b);             // bare v_sqrt_f32 (~1 ulp)
      // (d2-d3)^2 = a+b-2*sqrt(ab);  S = max(0, 1 - 100*(a+b) + 200*sqrt(ab))
      float w  = fmaf(a + b, -100.0f, 1.0f);
      w = fmaf(s, 200.0f, w);
      w = fmaxf(w, 0.0f);
      acc[u] = fmaf(w, vj, acc[u]);
    }
  }
#pragma unroll
  for (int u = 0; u < IPT; ++u)
    atomicAdd(&vdst[i0 + u * IBLK], acc[u] * RESCALE);
}

// out = v / (||v||_2 + 1e-6), float32; each block redundantly computes the norm.
__global__ __launch_bounds__(256) void finalize_kernel(
    const float* __restrict__ v, float* __restrict__ out) {
  const int tid = threadIdx.x;
  float ss = 0.0f;
  for (int k = tid; k < NPTS; k += 256) { float x = v[k]; ss = fmaf(x, x, ss); }
  for (int off = 32; off > 0; off >>= 1) ss += __shfl_down(ss, off, 64);
  __shared__ float wsum[4];
  if ((tid & 63) == 0) wsum[tid >> 6] = ss;
  __syncthreads();
  float inv = 1.0f / (sqrtf(wsum[0] + wsum[1] + wsum[2] + wsum[3]) + 1e-6f);
  int i = blockIdx.x * 256 + tid;
  out[i] = v[i] * inv;
}

extern "C" void kernel_launch(void* const* d_in, const int* in_sizes, int n_in,
                              void* d_out, int out_size, void* d_ws, size_t ws_size,
                              hipStream_t stream) {
  const float* p2 = (const float*)d_in[0];   // 6144 x 2, float32
  const float* p3 = (const float*)d_in[1];   // 6144 x 3, float32
  float* out = (float*)d_out;                // 6144, float32

  float* w = (float*)d_ws;
  float4* rec = (float4*)w;           // 6144 float4
  float*  z3a = w + 24576;            // 6144
  float*  buf[3] = { w + 32768, w + 40960, w + 49152 };  // v triple-buffer

  prep_kernel<<<NPTS / 128, 128, 0, stream>>>(p2, p3, rec, z3a, buf[0], buf[1]);

  for (int k = 0; k < 10; ++k) {
    matvec_kernel<<<NIBLK * JPART, IBLK, 0, stream>>>(
        rec, z3a, buf[k % 3], buf[(k + 1) % 3], buf[(k + 2) % 3]);
  }

  // after 10 iters, result is in buf[(9+1)%3] == buf[1]
  finalize_kernel<<<NPTS / 256, 256, 0, stream>>>(buf[1], out);
}